// Round 15
// baseline (415.258 us; speedup 1.0000x reference)
//
#include <hip/hip_runtime.h>
#include <math.h>

#define NB 2048
#define NT 512
#define ND 64

typedef float    f32x4 __attribute__((ext_vector_type(4)));
typedef short    s16x8 __attribute__((ext_vector_type(8)));

#define MFMA32(A,B,C) __builtin_amdgcn_mfma_f32_16x16x32_bf16((A),(B),(C),0,0,0)

#if __has_builtin(__builtin_amdgcn_exp2f)
#define EXP2F(x) __builtin_amdgcn_exp2f(x)
#else
#define EXP2F(x) __expf((x) * 0.6931471805599453f)
#endif
#if __has_builtin(__builtin_amdgcn_logf)
#define LOG2F(x) __builtin_amdgcn_logf(x)
#else
#define LOG2F(x) (__logf(x) * 1.4426950408889634f)
#endif
#if __has_builtin(__builtin_amdgcn_rcpf)
#define RCPF(x) __builtin_amdgcn_rcpf(x)
#else
#define RCPF(x) __fdividef(1.0f, (x))
#endif

// Pure-C bf16 round-to-nearest-even -- init-time only.
__device__ __forceinline__ unsigned short bf16rn(float f) {
  unsigned u = __float_as_uint(f);
  unsigned r = u + 0x7FFFu + ((u >> 16) & 1u);
  return (unsigned short)(r >> 16);
}
__device__ __forceinline__ unsigned pack2(float a, float b) {
  return (unsigned)bf16rn(a) | ((unsigned)bf16rn(b) << 16);
}
// Truncating bf16 pack (proven shift/and form; NOT v_perm -- see R10).
__device__ __forceinline__ unsigned pack2t(float a, float b) {
  return (__float_as_uint(a) >> 16) | (__float_as_uint(b) & 0xFFFF0000u);
}

union frag8 { s16x8 s8; unsigned u[4]; };

// pack D-layout f32x4 into a zero-padded MFMA32 A-frag (k = 8*(lane>>4)+i).
__device__ __forceinline__ s16x8 pack8t(f32x4 x) {
  frag8 r;
  r.u[0] = pack2t(x[0], x[1]);
  r.u[1] = pack2t(x[2], x[3]);
  r.u[2] = 0u; r.u[3] = 0u;
  return r.s8;
}

// ---------------------------------------------------------------------------
// Init (R8 layout): bf16 A-frags of W2 = logit(probs_y)*log2(e), rows
// PERMUTED (rho -> s = (4*(rho>>6)+(rho&3))*16 + ((rho>>2)&15)); base frags
// bf16 hi+lo in k-slots 0/1 of the w2 block.  Zeroes partials.
// ws: [0,32K) W frags, [32K,48K) base frags, [48K,56K) partials, [56K,64K) perm
// ---------------------------------------------------------------------------
__global__ void fhmm_init(const float* __restrict__ py,
                          unsigned short* __restrict__ ws16,
                          float* __restrict__ partials)
{
  const float LOG2E = 1.4426950408889634f;
  int t = blockIdx.x * 256 + threadIdx.x;
  if (t < 2048) partials[t] = 0.f;
  if (t < 2048) {
    int st = t >> 7, kk = (t >> 6) & 1, l = t & 63;
    int rho = st * 16 + (l & 15);
    int s = (4 * (rho >> 6) + (rho & 3)) * 16 + ((rho >> 2) & 15);
    int d0 = kk * 32 + 8 * (l >> 4);
    unsigned short* dst = ws16 + (size_t)t * 8;
#pragma unroll
    for (int i = 0; i < 8; ++i) {
      float p = py[s * 64 + d0 + i];
      dst[i] = bf16rn((logf(p) - log1pf(-p)) * LOG2E);
    }
  } else if (t < 3072) {
    int t2 = t - 2048;
    int st = t2 >> 6, l = t2 & 63;
    unsigned short v[8] = {0, 0, 0, 0, 0, 0, 0, 0};
    if (l < 16) {
      int rho = st * 16 + l;
      int s = (4 * (rho >> 6) + (rho & 3)) * 16 + ((rho >> 2) & 15);
      float base = 0.f;
      for (int d = 0; d < 64; ++d) base += log1pf(-py[s * 64 + d]);
      base *= LOG2E;
      unsigned short hi = bf16rn(base);
      float basehi = __uint_as_float(((unsigned)hi) << 16);
      v[0] = hi;
      v[1] = bf16rn(base - basehi);
    }
    unsigned short* dst = ws16 + (size_t)(2048 + t2) * 8;
#pragma unroll
    for (int i = 0; i < 8; ++i) dst[i] = v[i];
  }
}

// ---------------------------------------------------------------------------
// Fast counting sort by DESCENDING length, parallel scan.
// ---------------------------------------------------------------------------
__global__ void fhmm_sort(const int* __restrict__ lengths, int* __restrict__ perm)
{
  __shared__ int hist[512];
  __shared__ int cnt[512];
  __shared__ int sa[512], sb2[512];
  const int tid = threadIdx.x;
  hist[tid] = 0; hist[tid + 256] = 0;
  cnt[tid] = 0;  cnt[tid + 256] = 0;
  __syncthreads();
  int myb[8];
#pragma unroll
  for (int u = 0; u < 8; ++u) {
    int i = tid + 256 * u;
    myb[u] = 512 - lengths[i];
    atomicAdd(&hist[myb[u]], 1);
  }
  __syncthreads();
  sa[tid] = hist[tid]; sa[tid + 256] = hist[tid + 256];
  __syncthreads();
  int* src = sa; int* dst = sb2;
  for (int off = 1; off < 512; off <<= 1) {
    for (int k = tid; k < 512; k += 256)
      dst[k] = src[k] + ((k >= off) ? src[k - off] : 0);
    __syncthreads();
    int* tp = src; src = dst; dst = tp;
  }
#pragma unroll
  for (int u = 0; u < 8; ++u) {
    int i = tid + 256 * u;
    int b2 = myb[u];
    int pos = src[b2] - hist[b2] + atomicAdd(&cnt[b2], 1);
    perm[pos] = i;
  }
}

// ---------------------------------------------------------------------------
// Main (R15): TWO sequences per wave (ranks 2p, 2p+1 -- sorted, near-equal
// lengths) -> two independent recursion chains interleaved by the compiler
// inside one instruction stream (deterministic dual-ILP; 1024 waves =
// 1/SIMD so VGPRs are free).  Per-sequence math is EXACTLY R8's proven
// form: f32 G, 3-MFMA emission w/ folded base, same-step ones-MFMA
// normalizer p=(U*inv)*g (first-order stable; R14's lagged inv was
// second-order oscillatory -> clamps -> garbage).  LDS 2x16KB/wave = 128KB.
// ---------------------------------------------------------------------------
__global__ __launch_bounds__(256, 1) void fhmm_fwd2(
    const int* __restrict__ seqg, const int* __restrict__ lengths,
    const float* __restrict__ pw, const float* __restrict__ px,
    const void* __restrict__ wfrag, const int* __restrict__ perm,
    float* __restrict__ partials)
{
  __shared__ f32x4 e_lds[4][2][1024];   // [wave][seq][slot], 128KB total

  const int tid = threadIdx.x;
  const int wv = tid >> 6, j = tid & 63;
  const int q = j >> 4, tl = j & 15;
  const int pi = (blockIdx.x << 2) | wv;     // pair index 0..1023
  const int bA = perm[2 * pi];
  const int bB = perm[2 * pi + 1];
  if (bA < 0 || bA >= NB || bB < 0 || bB >= NB) return;
  f32x4* eA = e_lds[wv][0];
  f32x4* eB = e_lds[wv][1];
  const s16x8* wf_g = (const s16x8*)wfrag;
  const s16x8* w2_g = wf_g + 2048;

  // Tw/Tx zero-padded B-frags: b[i<4] = T[4q+i][tl], b[4..7] = 0
  s16x8 twb8, txb8;
  {
    frag8 a, c;
    a.u[0] = pack2(pw[(4 * q + 0) * 16 + tl], pw[(4 * q + 1) * 16 + tl]);
    a.u[1] = pack2(pw[(4 * q + 2) * 16 + tl], pw[(4 * q + 3) * 16 + tl]);
    a.u[2] = 0u; a.u[3] = 0u;
    c.u[0] = pack2(px[(4 * q + 0) * 16 + tl], px[(4 * q + 1) * 16 + tl]);
    c.u[1] = pack2(px[(4 * q + 2) * 16 + tl], px[(4 * q + 3) * 16 + tl]);
    c.u[2] = 0u; c.u[3] = 0u;
    twb8 = a.s8; txb8 = c.s8;
  }

  s16x8 f2 = {0, 0, 0, 0, 0, 0, 0, 0};   // ones in k-rows 0,1 (base column)
  if (q == 0) { f2[0] = (short)0x3F80; f2[1] = (short)0x3F80; }

  s16x8 ones8;                            // all-ones B (sum collapser)
  {
    frag8 o;
    o.u[0] = 0x3F803F80u; o.u[1] = 0x3F803F80u;
    o.u[2] = 0x3F803F80u; o.u[3] = 0x3F803F80u;
    ones8 = o.s8;
  }

  const int lenA = lengths[bA];
  const int lenB = lengths[bB];
  const int* ybaseA = seqg + (size_t)bA * NT * ND;
  const int* ybaseB = seqg + (size_t)bB * NT * ND;
  const f32x4 z4 = {0.f, 0.f, 0.f, 0.f};

  f32x4 pA = z4, pB = z4;                 // alpha0 = delta(0,0)
  if (j == 0) { pA[0] = 1.f; pB[0] = 1.f; }

  int4 ya0A, ya1A, yb0A, yb1A, ya0B, ya1B, yb0B, yb1B;
  s16x8 f0A, f1A, f0B, f1B;
  f32x4 gvA, gvB;

#define LOADY(S, ROWBASE)                                                  \
  {                                                                        \
    int row_ = (ROWBASE) + tl;                                             \
    if (row_ > len##S - 1) row_ = len##S - 1;  /* clamp: OOB-safe */       \
    const int* yr_ = ybase##S + (size_t)row_ * ND + 8 * q;                 \
    ya0##S = ((const int4*)yr_)[0];                                        \
    ya1##S = ((const int4*)yr_)[1];                                        \
    yb0##S = ((const int4*)(yr_ + 32))[0];                                 \
    yb1##S = ((const int4*)(yr_ + 32))[1];                                 \
  }

#define BUILDF(S)                                                          \
  {                                                                        \
    frag8 f0u_, f1u_;                                                      \
    f0u_.u[0] = (ya0##S.x ? 0x3F80u : 0u) | (ya0##S.y ? 0x3F800000u : 0u); \
    f0u_.u[1] = (ya0##S.z ? 0x3F80u : 0u) | (ya0##S.w ? 0x3F800000u : 0u); \
    f0u_.u[2] = (ya1##S.x ? 0x3F80u : 0u) | (ya1##S.y ? 0x3F800000u : 0u); \
    f0u_.u[3] = (ya1##S.z ? 0x3F80u : 0u) | (ya1##S.w ? 0x3F800000u : 0u); \
    f1u_.u[0] = (yb0##S.x ? 0x3F80u : 0u) | (yb0##S.y ? 0x3F800000u : 0u); \
    f1u_.u[1] = (yb0##S.z ? 0x3F80u : 0u) | (yb0##S.w ? 0x3F800000u : 0u); \
    f1u_.u[2] = (yb1##S.x ? 0x3F80u : 0u) | (yb1##S.y ? 0x3F800000u : 0u); \
    f1u_.u[3] = (yb1##S.z ? 0x3F80u : 0u) | (yb1##S.w ? 0x3F800000u : 0u); \
    f0##S = f0u_.s8; f1##S = f1u_.s8;                                      \
  }

#define EMIT16(S, EO)                                                      \
  {                                                                        \
    _Pragma("unroll")                                                      \
    for (int st = 0; st < 16; ++st) {                                      \
      f32x4 acc_ = MFMA32(w2_g[st * 64 + j], f2, z4);                      \
      acc_ = MFMA32(wf_g[(2 * st + 0) * 64 + j], f0##S, acc_);             \
      acc_ = MFMA32(wf_g[(2 * st + 1) * 64 + j], f1##S, acc_);             \
      f32x4 G_;                                                            \
      G_[0] = EXP2F(fminf(acc_[0] - R##S, 80.f));                          \
      G_[1] = EXP2F(fminf(acc_[1] - R##S, 80.f));                          \
      G_[2] = EXP2F(fminf(acc_[2] - R##S, 80.f));                          \
      G_[3] = EXP2F(fminf(acc_[3] - R##S, 80.f));                          \
      (EO)[tl * 64 + ((st * 4 + q) ^ tl)] = G_;                            \
    }                                                                      \
  }

// R8-proven step: same-step normalizer, scale-order invariant (U*inv)*g.
#define STEP(S, IT, EO)                                                    \
  {                                                                        \
    const f32x4 g_ = gv##S;                                                \
    const int itn_ = ((IT) + 1) & 15;                                      \
    gv##S = (EO)[itn_ * 64 + (j ^ itn_)];                                  \
    s16x8 vb_ = pack8t(p##S);                                              \
    f32x4 P_  = MFMA32(vb_, twb8, z4);                                     \
    f32x4 S1_ = MFMA32(vb_, ones8, z4);                                    \
    f32x4 U_  = MFMA32(pack8t(P_), txb8, z4);                              \
    f32x4 S2_ = MFMA32(pack8t(S1_), ones8, z4);                            \
    const float s_   = fmaxf(S2_[0], 1e-30f);                              \
    const float inv_ = RCPF(s_);                                           \
    Ls##S += LOG2F(s_);                                                    \
    p##S[0] = (U_[0] * inv_) * g_[0];                                      \
    p##S[1] = (U_[1] * inv_) * g_[1];                                      \
    p##S[2] = (U_[2] * inv_) * g_[2];                                      \
    p##S[3] = (U_[3] * inv_) * g_[3];                                      \
  }

  LOADY(A, 0)
  LOADY(B, 0)

  float L2A = 0.f, LsA = 0.f, RA = 0.f;
  float L2B = 0.f, LsB = 0.f, RB = 0.f;

  for (int t0 = 0; t0 < lenA; t0 += 16) {
    const int nsA = (lenA - t0 < 16) ? (lenA - t0) : 16;
    int nsB = lenB - t0;
    nsB = (nsB < 0) ? 0 : ((nsB > 16) ? 16 : nsB);

    BUILDF(A)
    if (nsB > 0) BUILDF(B)
    if (t0 + 16 < lenA) LOADY(A, t0 + 16)
    if (t0 + 16 < lenB) LOADY(B, t0 + 16)

    EMIT16(A, eA)
    if (nsB > 0) EMIT16(B, eB)

    const float Ls0A = LsA, Ls0B = LsB;
    gvA = eA[j];
    gvB = eB[j];
    if (nsA == 16 && nsB == 16) {        // common case: dual unrolled
#define DSTEP(IT) { STEP(A, IT, eA) STEP(B, IT, eB) }
      DSTEP(0)  DSTEP(1)  DSTEP(2)  DSTEP(3)
      DSTEP(4)  DSTEP(5)  DSTEP(6)  DSTEP(7)
      DSTEP(8)  DSTEP(9)  DSTEP(10) DSTEP(11)
      DSTEP(12) DSTEP(13) DSTEP(14) DSTEP(15)
#undef DSTEP
    } else {                             // tail: per-seq trip counts
      for (int it = 0; it < 16; ++it) {
        if (it < nsA) STEP(A, it, eA)
        if (it < nsB) STEP(B, it, eB)
      }
    }
    L2A += (float)nsA * RA;
    RA  += (LsA - Ls0A) * 0.0625f;
    L2B += (float)nsB * RB;
    RB  += (LsB - Ls0B) * 0.0625f;
  }

  // final totals via ones-MFMA
  {
    f32x4 F1 = MFMA32(pack8t(pA), ones8, z4);
    f32x4 F2 = MFMA32(pack8t(F1), ones8, z4);
    float sf = fmaxf(F2[0], 1e-35f);
    float L = (L2A + LsA + LOG2F(sf)) * 0.6931471805599453f;
    if (j == 0) partials[bA] = L;
  }
  {
    f32x4 F1 = MFMA32(pack8t(pB), ones8, z4);
    f32x4 F2 = MFMA32(pack8t(F1), ones8, z4);
    float sf = fmaxf(F2[0], 1e-35f);
    float L = (L2B + LsB + LOG2F(sf)) * 0.6931471805599453f;
    if (j == 0) partials[bB] = L;
  }
#undef LOADY
#undef BUILDF
#undef EMIT16
#undef STEP
}

// ---------------------------------------------------------------------------
// Round-1 fallback (block per sequence) for small workspace.
// ---------------------------------------------------------------------------
__global__ __launch_bounds__(256, 3) void fhmm_fwd1(
    const int* __restrict__ seq, const int* __restrict__ lengths,
    const float* __restrict__ pw, const float* __restrict__ px,
    const float* __restrict__ py, float* __restrict__ partials,
    float* __restrict__ out)
{
  const int b = blockIdx.x, tid = threadIdx.x;
  const int wp = tid >> 4, xc = tid & 15;
  float Twc[16], Txc[16], W[64], base = 0.f;
#pragma unroll
  for (int w = 0; w < 16; ++w) Twc[w] = pw[w * 16 + wp];
#pragma unroll
  for (int x = 0; x < 16; ++x) Txc[x] = px[x * 16 + xc];
#pragma unroll
  for (int d = 0; d < 64; ++d) {
    float pv = py[tid * 64 + d];
    W[d] = logf(pv) - log1pf(-pv);
    base += log1pf(-pv);
  }
  __shared__ __align__(16) float yf[64];
  __shared__ __align__(16) float v_s[256];
  __shared__ __align__(16) float tmp_s[256];
  __shared__ float red[8];
  const int len = lengths[b];
  const int* yb = seq + (size_t)b * (NT * ND);
  v_s[tid] = (tid == 0) ? 1.f : 0.f;
  float L = 0.f, ynext = 0.f;
  if (tid < 64) ynext = (float)yb[tid];
  for (int t = 0; t < len; ++t) {
    if (tid < 64) yf[tid] = ynext;
    __syncthreads();
    if (tid < 64 && (t + 1) < len) ynext = (float)yb[(t + 1) * ND + tid];
    float e0 = base, e1 = 0.f, e2 = 0.f, e3 = 0.f;
    const float4* y4p = (const float4*)yf;
#pragma unroll
    for (int i = 0; i < 16; ++i) {
      float4 y4 = y4p[i];
      e0 = fmaf(y4.x, W[4 * i + 0], e0); e1 = fmaf(y4.y, W[4 * i + 1], e1);
      e2 = fmaf(y4.z, W[4 * i + 2], e2); e3 = fmaf(y4.w, W[4 * i + 3], e3);
    }
    float e = (e0 + e1) + (e2 + e3);
    float s1a = 0.f, s1b = 0.f;
#pragma unroll
    for (int w = 0; w < 16; w += 2) {
      s1a = fmaf(Twc[w], v_s[w * 16 + xc], s1a);
      s1b = fmaf(Twc[w + 1], v_s[(w + 1) * 16 + xc], s1b);
    }
    tmp_s[tid] = s1a + s1b;
    float mm = e;
#pragma unroll
    for (int off = 32; off; off >>= 1) mm = fmaxf(mm, __shfl_xor(mm, off));
    if ((tid & 63) == 0) red[tid >> 6] = mm;
    __syncthreads();
    mm = fmaxf(fmaxf(red[0], red[1]), fmaxf(red[2], red[3]));
    float q0 = 0.f, q1 = 0.f;
    const float4* t4p = (const float4*)(tmp_s + wp * 16);
#pragma unroll
    for (int i = 0; i < 4; ++i) {
      float4 t4 = t4p[i];
      q0 = fmaf(t4.x, Txc[4 * i + 0], q0); q1 = fmaf(t4.y, Txc[4 * i + 1], q1);
      q0 = fmaf(t4.z, Txc[4 * i + 2], q0); q1 = fmaf(t4.w, Txc[4 * i + 3], q1);
    }
    float val = (q0 + q1) * __expf(e - mm);
    float s = val;
#pragma unroll
    for (int off = 32; off; off >>= 1) s += __shfl_xor(s, off);
    if ((tid & 63) == 0) red[4 + (tid >> 6)] = s;
    __syncthreads();
    s = (red[4] + red[5]) + (red[6] + red[7]);
    L += __logf(s) + mm;
    v_s[tid] = val * (1.0f / s);
  }
  if (partials) { if (tid == 0) partials[b] = L; }
  else { if (tid == 0) atomicAdd(out, L); }
}

// ---------------------------------------------------------------------------
// Finalize: deterministic tree-sum of per-sequence LLs + priors.
// ---------------------------------------------------------------------------
__global__ void fhmm_finalize(const float* __restrict__ partials,
                              const float* __restrict__ pw,
                              const float* __restrict__ px,
                              const float* __restrict__ py,
                              float* __restrict__ out)
{
  const int tid = threadIdx.x;
  float a = 0.f;
  if (partials) {
#pragma unroll
    for (int i = 0; i < 8; ++i) a += partials[tid + 256 * i];
  }
  {
    int i = tid >> 4, j = tid & 15;
    if (i != j) a += -0.9f * (logf(pw[tid]) + logf(px[tid]));
  }
  for (int k = 0; k < 64; ++k) {
    float p = py[tid * 64 + k];
    a += -0.9f * logf(p) - 0.1f * log1pf(-p);
  }
  __shared__ float red[256];
  red[tid] = a;
  __syncthreads();
  for (int s = 128; s > 0; s >>= 1) {
    if (tid < s) red[tid] += red[tid + s];
    __syncthreads();
  }
  if (tid == 0) {
    const float cst =
        2.f * (16.f * 0.2846828704729192f - 240.f * 2.2527126517342055f)
        - (2.2527126517342055f + 0.0663762397347443f) * 16384.f;
    out[0] = red[0] + cst;
  }
}

extern "C" void kernel_launch(void* const* d_in, const int* in_sizes, int n_in,
                              void* d_out, int out_size, void* d_ws, size_t ws_size,
                              hipStream_t stream) {
  const int*   seq = (const int*)d_in[0];
  const int*   len = (const int*)d_in[1];
  const float* pw  = (const float*)d_in[2];
  const float* px  = (const float*)d_in[3];
  const float* py  = (const float*)d_in[4];
  float*       out = (float*)d_out;

  const size_t NEED = 65536;  // 32K wfrag + 16K base + 8K partials + 8K perm
  if (ws_size >= NEED) {
    unsigned short* wf = (unsigned short*)d_ws;
    float* partials = (float*)((char*)d_ws + 49152);
    int*   perm     = (int*)((char*)d_ws + 57344);
    fhmm_init<<<12, 256, 0, stream>>>(py, wf, partials);
    fhmm_sort<<<1, 256, 0, stream>>>(len, perm);
    fhmm_fwd2<<<256, 256, 0, stream>>>(seq, len, pw, px, (const void*)wf, perm, partials);
    fhmm_finalize<<<1, 256, 0, stream>>>(partials, pw, px, py, out);
  } else if (ws_size >= 2048 * sizeof(float)) {
    float* partials = (float*)d_ws;
    fhmm_fwd1<<<NB, 256, 0, stream>>>(seq, len, pw, px, py, partials, out);
    fhmm_finalize<<<1, 256, 0, stream>>>(partials, pw, px, py, out);
  } else {
    fhmm_finalize<<<1, 256, 0, stream>>>(nullptr, pw, px, py, out);
    fhmm_fwd1<<<NB, 256, 0, stream>>>(seq, len, pw, px, py, nullptr, out);
  }
}

// Round 16
// 200.800 us; speedup vs baseline: 2.0680x; 2.0680x over previous
//
#include <hip/hip_runtime.h>
#include <math.h>

#define NB 2048
#define NT 512
#define ND 64

typedef float    f32x4 __attribute__((ext_vector_type(4)));
typedef short    s16x8 __attribute__((ext_vector_type(8)));

#define MFMA32(A,B,C) __builtin_amdgcn_mfma_f32_16x16x32_bf16((A),(B),(C),0,0,0)

#if __has_builtin(__builtin_amdgcn_exp2f)
#define EXP2F(x) __builtin_amdgcn_exp2f(x)
#else
#define EXP2F(x) __expf((x) * 0.6931471805599453f)
#endif
#if __has_builtin(__builtin_amdgcn_logf)
#define LOG2F(x) __builtin_amdgcn_logf(x)
#else
#define LOG2F(x) (__logf(x) * 1.4426950408889634f)
#endif
#if __has_builtin(__builtin_amdgcn_rcpf)
#define RCPF(x) __builtin_amdgcn_rcpf(x)
#else
#define RCPF(x) __fdividef(1.0f, (x))
#endif

// Pure-C bf16 round-to-nearest-even -- init-time only.
__device__ __forceinline__ unsigned short bf16rn(float f) {
  unsigned u = __float_as_uint(f);
  unsigned r = u + 0x7FFFu + ((u >> 16) & 1u);
  return (unsigned short)(r >> 16);
}
__device__ __forceinline__ unsigned pack2(float a, float b) {
  return (unsigned)bf16rn(a) | ((unsigned)bf16rn(b) << 16);
}
// Truncating bf16 pack (proven shift/and form; NOT v_perm -- see R10).
__device__ __forceinline__ unsigned pack2t(float a, float b) {
  return (__float_as_uint(a) >> 16) | (__float_as_uint(b) & 0xFFFF0000u);
}

union frag8 { s16x8 s8; unsigned u[4]; };

// pack D-layout f32x4 into a zero-padded MFMA32 A-frag (k = 8*(lane>>4)+i).
__device__ __forceinline__ s16x8 pack8t(f32x4 x) {
  frag8 r;
  r.u[0] = pack2t(x[0], x[1]);
  r.u[1] = pack2t(x[2], x[3]);
  r.u[2] = 0u; r.u[3] = 0u;
  return r.s8;
}

// ---------------------------------------------------------------------------
// Merged init + sort (single launch; block 12 = sort, blocks 0-11 = init).
// Init (R8 layout): bf16 A-frags of W2 = logit(probs_y)*log2(e), rows
// PERMUTED (rho -> s = (4*(rho>>6)+(rho&3))*16 + ((rho>>2)&15)); base frags
// bf16 hi+lo in k-slots 0/1 of the w2 block.  Zeroes partials.
// Sort: counting sort by DESCENDING length, parallel Hillis-Steele scan.
// ws: [0,32K) W frags, [32K,48K) base frags, [48K,56K) partials, [56K,64K) perm
// ---------------------------------------------------------------------------
__global__ void fhmm_init_sort(const float* __restrict__ py,
                               const int* __restrict__ lengths,
                               unsigned short* __restrict__ ws16,
                               float* __restrict__ partials,
                               int* __restrict__ perm)
{
  const float LOG2E = 1.4426950408889634f;
  if (blockIdx.x == 12) {              // ---- sort block (verbatim R8 sort) ----
    __shared__ int hist[512];
    __shared__ int cnt[512];
    __shared__ int sa[512], sb2[512];
    const int tid = threadIdx.x;
    hist[tid] = 0; hist[tid + 256] = 0;
    cnt[tid] = 0;  cnt[tid + 256] = 0;
    __syncthreads();
    int myb[8];
#pragma unroll
    for (int u = 0; u < 8; ++u) {
      int i = tid + 256 * u;
      myb[u] = 512 - lengths[i];
      atomicAdd(&hist[myb[u]], 1);
    }
    __syncthreads();
    sa[tid] = hist[tid]; sa[tid + 256] = hist[tid + 256];
    __syncthreads();
    int* src = sa; int* dst = sb2;
    for (int off = 1; off < 512; off <<= 1) {
      for (int k = tid; k < 512; k += 256)
        dst[k] = src[k] + ((k >= off) ? src[k - off] : 0);
      __syncthreads();
      int* tp = src; src = dst; dst = tp;
    }
#pragma unroll
    for (int u = 0; u < 8; ++u) {
      int i = tid + 256 * u;
      int b2 = myb[u];
      int pos = src[b2] - hist[b2] + atomicAdd(&cnt[b2], 1);
      perm[pos] = i;
    }
    return;
  }
  int t = blockIdx.x * 256 + threadIdx.x;
  if (t < 2048) partials[t] = 0.f;
  if (t < 2048) {
    int st = t >> 7, kk = (t >> 6) & 1, l = t & 63;
    int rho = st * 16 + (l & 15);
    int s = (4 * (rho >> 6) + (rho & 3)) * 16 + ((rho >> 2) & 15);
    int d0 = kk * 32 + 8 * (l >> 4);
    unsigned short* dst = ws16 + (size_t)t * 8;
#pragma unroll
    for (int i = 0; i < 8; ++i) {
      float p = py[s * 64 + d0 + i];
      dst[i] = bf16rn((logf(p) - log1pf(-p)) * LOG2E);
    }
  } else if (t < 3072) {
    int t2 = t - 2048;
    int st = t2 >> 6, l = t2 & 63;
    unsigned short v[8] = {0, 0, 0, 0, 0, 0, 0, 0};
    if (l < 16) {
      int rho = st * 16 + l;
      int s = (4 * (rho >> 6) + (rho & 3)) * 16 + ((rho >> 2) & 15);
      float base = 0.f;
      for (int d = 0; d < 64; ++d) base += log1pf(-py[s * 64 + d]);
      base *= LOG2E;
      unsigned short hi = bf16rn(base);
      float basehi = __uint_as_float(((unsigned)hi) << 16);
      v[0] = hi;
      v[1] = bf16rn(base - basehi);
    }
    unsigned short* dst = ws16 + (size_t)(2048 + t2) * 8;
#pragma unroll
    for (int i = 0; i < 8; ++i) dst[i] = v[i];
  }
}

// ---------------------------------------------------------------------------
// Main (EXACT R8 kernel, proven 178us fwd2 / absmax 0.0): 256-thread blocks
// (4 waves), 512 blocks; complementary remap (bid<256 ? bid : 767-bid) ->
// uniform per-CU work.  Emission: G = exp2(E - R) incl. base, f32 in LDS
// (16KB/wave), 3 MFMAs/st.  Recursion: register-only MFMA free-transpose
// chain, 1-deep G prefetch, same-step ones-MFMA normalizer.  SCALE-ORDER
// INVARIANT: (U*inv) first, then *g (R10/R11: (U*g) first underflows f32).
// ---------------------------------------------------------------------------
__global__ __launch_bounds__(256, 2) void fhmm_fwd2(
    const int* __restrict__ seq, const int* __restrict__ lengths,
    const float* __restrict__ pw, const float* __restrict__ px,
    const void* __restrict__ wfrag, const int* __restrict__ perm,
    float* __restrict__ partials)
{
  __shared__ f32x4 e_lds[4][1024];   // 16KB per wave: [16 steps][64 slots] f32x4

  const int tid = threadIdx.x;
  const int wv = tid >> 6, j = tid & 63;
  const int q = j >> 4, tl = j & 15;
  const int bid = blockIdx.x;
  const int lb  = (bid < 256) ? bid : (767 - bid);   // complementary (R8)
  const int b = perm[(lb << 2) | wv];
  if (b < 0 || b >= NB) return;
  f32x4* e_w = e_lds[wv];
  const s16x8* wf_g = (const s16x8*)wfrag;
  const s16x8* w2_g = wf_g + 2048;

  // Tw/Tx zero-padded B-frags: b[i<4] = T[4q+i][tl], b[4..7] = 0
  s16x8 twb8, txb8;
  {
    frag8 a, c;
    a.u[0] = pack2(pw[(4 * q + 0) * 16 + tl], pw[(4 * q + 1) * 16 + tl]);
    a.u[1] = pack2(pw[(4 * q + 2) * 16 + tl], pw[(4 * q + 3) * 16 + tl]);
    a.u[2] = 0u; a.u[3] = 0u;
    c.u[0] = pack2(px[(4 * q + 0) * 16 + tl], px[(4 * q + 1) * 16 + tl]);
    c.u[1] = pack2(px[(4 * q + 2) * 16 + tl], px[(4 * q + 3) * 16 + tl]);
    c.u[2] = 0u; c.u[3] = 0u;
    twb8 = a.s8; txb8 = c.s8;
  }

  s16x8 f2 = {0, 0, 0, 0, 0, 0, 0, 0};   // ones in k-rows 0,1 (base column)
  if (q == 0) { f2[0] = (short)0x3F80; f2[1] = (short)0x3F80; }

  s16x8 ones8;                            // all-ones B (sum collapser)
  {
    frag8 o;
    o.u[0] = 0x3F803F80u; o.u[1] = 0x3F803F80u;
    o.u[2] = 0x3F803F80u; o.u[3] = 0x3F803F80u;
    ones8 = o.s8;
  }

  f32x4 p = {0.f, 0.f, 0.f, 0.f};        // V in D-layout; alpha0 = delta(0,0)
  if (j == 0) p[0] = 1.f;

  const int len = lengths[b];
  const int* ybase = seq + (size_t)b * NT * ND;

  int4 ya0, ya1, yb0, yb1;
  {
    const int* yr = ybase + (size_t)tl * ND + 8 * q;
    const int4* pp  = (const int4*)yr;
    const int4* pp2 = (const int4*)(yr + 32);
    ya0 = pp[0]; ya1 = pp[1]; yb0 = pp2[0]; yb1 = pp2[1];
  }

  float L2 = 0.f, Ls = 0.f, R = 0.f;
  const f32x4 z4 = {0.f, 0.f, 0.f, 0.f};

  for (int t0 = 0; t0 < len; t0 += 16) {
    union { s16x8 s; unsigned u[4]; } f0u, f1u;
    f0u.u[0] = (ya0.x ? 0x3F80u : 0u) | (ya0.y ? 0x3F800000u : 0u);
    f0u.u[1] = (ya0.z ? 0x3F80u : 0u) | (ya0.w ? 0x3F800000u : 0u);
    f0u.u[2] = (ya1.x ? 0x3F80u : 0u) | (ya1.y ? 0x3F800000u : 0u);
    f0u.u[3] = (ya1.z ? 0x3F80u : 0u) | (ya1.w ? 0x3F800000u : 0u);
    f1u.u[0] = (yb0.x ? 0x3F80u : 0u) | (yb0.y ? 0x3F800000u : 0u);
    f1u.u[1] = (yb0.z ? 0x3F80u : 0u) | (yb0.w ? 0x3F800000u : 0u);
    f1u.u[2] = (yb1.x ? 0x3F80u : 0u) | (yb1.y ? 0x3F800000u : 0u);
    f1u.u[3] = (yb1.z ? 0x3F80u : 0u) | (yb1.w ? 0x3F800000u : 0u);
    const s16x8 f0 = f0u.s, f1 = f1u.s;

    if (t0 + 16 < len) {   // prefetch next chunk's y under compute
      const int* yr = ybase + (size_t)(t0 + 16 + tl) * ND + 8 * q;
      const int4* pp  = (const int4*)yr;
      const int4* pp2 = (const int4*)(yr + 32);
      ya0 = pp[0]; ya1 = pp[1]; yb0 = pp2[0]; yb1 = pp2[1];
    }

    // ---- emission: G = exp2(E - R) incl. base, f32, 3 MFMAs/st ----
#pragma unroll
    for (int st = 0; st < 16; ++st) {
      f32x4 acc = MFMA32(w2_g[st * 64 + j], f2, z4);
      acc = MFMA32(wf_g[(2 * st + 0) * 64 + j], f0, acc);
      acc = MFMA32(wf_g[(2 * st + 1) * 64 + j], f1, acc);
      f32x4 G;
      G[0] = EXP2F(fminf(acc[0] - R, 80.f));
      G[1] = EXP2F(fminf(acc[1] - R, 80.f));
      G[2] = EXP2F(fminf(acc[2] - R, 80.f));
      G[3] = EXP2F(fminf(acc[3] - R, 80.f));
      e_w[tl * 64 + ((st * 4 + q) ^ tl)] = G;
    }

    // ---- recursion: register-only MFMA chain; no exp2/unpack/cross-lane ----
    const int nsteps = (len - t0 < 16) ? (len - t0) : 16;
    float LsC = 0.f;
    f32x4 gv = e_w[j];            // it=0 slot (j ^ 0 = j)
    for (int it = 0; it < nsteps; ++it) {
      const f32x4 g = gv;
      const int itn = (it + 1) & 15;
      gv = e_w[itn * 64 + (j ^ itn)];          // prefetch next step
      s16x8 vb = pack8t(p);                    // D-of-prev reused as A = V^T
      f32x4 P  = MFMA32(vb, twb8, z4);         // P  = V^T * Tw
      f32x4 S1 = MFMA32(vb, ones8, z4);        // row sums
      f32x4 U  = MFMA32(pack8t(P), txb8, z4);  // U  = Tw^T V Tx
      f32x4 S2 = MFMA32(pack8t(S1), ones8, z4);// grand total (mass of p_prev)
      const float s   = fmaxf(S2[0], 1e-30f);
      const float inv = RCPF(s);
      LsC += LOG2F(s);
      f32x4 pn;
      pn[0] = (U[0] * inv) * g[0];             // U*inv <= O(1); * G bounded
      pn[1] = (U[1] * inv) * g[1];
      pn[2] = (U[2] * inv) * g[2];
      pn[3] = (U[3] * inv) * g[3];
      p = pn;
    }
    L2 += (float)nsteps * R;                    // applied shift accounting
    Ls += LsC;
    R  += LsC * 0.0625f;                        // track typical emission scale
  }
  // final total of p via ones-MFMA
  {
    f32x4 F1 = MFMA32(pack8t(p), ones8, z4);
    f32x4 F2 = MFMA32(pack8t(F1), ones8, z4);
    float sf = fmaxf(F2[0], 1e-35f);
    float L = (L2 + Ls + LOG2F(sf)) * 0.6931471805599453f;
    if (j == 0) partials[b] = L;
  }
}

// ---------------------------------------------------------------------------
// Round-1 fallback (block per sequence) for small workspace.
// ---------------------------------------------------------------------------
__global__ __launch_bounds__(256, 3) void fhmm_fwd1(
    const int* __restrict__ seq, const int* __restrict__ lengths,
    const float* __restrict__ pw, const float* __restrict__ px,
    const float* __restrict__ py, float* __restrict__ partials,
    float* __restrict__ out)
{
  const int b = blockIdx.x, tid = threadIdx.x;
  const int wp = tid >> 4, xc = tid & 15;
  float Twc[16], Txc[16], W[64], base = 0.f;
#pragma unroll
  for (int w = 0; w < 16; ++w) Twc[w] = pw[w * 16 + wp];
#pragma unroll
  for (int x = 0; x < 16; ++x) Txc[x] = px[x * 16 + xc];
#pragma unroll
  for (int d = 0; d < 64; ++d) {
    float pv = py[tid * 64 + d];
    W[d] = logf(pv) - log1pf(-pv);
    base += log1pf(-pv);
  }
  __shared__ __align__(16) float yf[64];
  __shared__ __align__(16) float v_s[256];
  __shared__ __align__(16) float tmp_s[256];
  __shared__ float red[8];
  const int len = lengths[b];
  const int* yb = seq + (size_t)b * (NT * ND);
  v_s[tid] = (tid == 0) ? 1.f : 0.f;
  float L = 0.f, ynext = 0.f;
  if (tid < 64) ynext = (float)yb[tid];
  for (int t = 0; t < len; ++t) {
    if (tid < 64) yf[tid] = ynext;
    __syncthreads();
    if (tid < 64 && (t + 1) < len) ynext = (float)yb[(t + 1) * ND + tid];
    float e0 = base, e1 = 0.f, e2 = 0.f, e3 = 0.f;
    const float4* y4p = (const float4*)yf;
#pragma unroll
    for (int i = 0; i < 16; ++i) {
      float4 y4 = y4p[i];
      e0 = fmaf(y4.x, W[4 * i + 0], e0); e1 = fmaf(y4.y, W[4 * i + 1], e1);
      e2 = fmaf(y4.z, W[4 * i + 2], e2); e3 = fmaf(y4.w, W[4 * i + 3], e3);
    }
    float e = (e0 + e1) + (e2 + e3);
    float s1a = 0.f, s1b = 0.f;
#pragma unroll
    for (int w = 0; w < 16; w += 2) {
      s1a = fmaf(Twc[w], v_s[w * 16 + xc], s1a);
      s1b = fmaf(Twc[w + 1], v_s[(w + 1) * 16 + xc], s1b);
    }
    tmp_s[tid] = s1a + s1b;
    float mm = e;
#pragma unroll
    for (int off = 32; off; off >>= 1) mm = fmaxf(mm, __shfl_xor(mm, off));
    if ((tid & 63) == 0) red[tid >> 6] = mm;
    __syncthreads();
    mm = fmaxf(fmaxf(red[0], red[1]), fmaxf(red[2], red[3]));
    float q0 = 0.f, q1 = 0.f;
    const float4* t4p = (const float4*)(tmp_s + wp * 16);
#pragma unroll
    for (int i = 0; i < 4; ++i) {
      float4 t4 = t4p[i];
      q0 = fmaf(t4.x, Txc[4 * i + 0], q0); q1 = fmaf(t4.y, Txc[4 * i + 1], q1);
      q0 = fmaf(t4.z, Txc[4 * i + 2], q0); q1 = fmaf(t4.w, Txc[4 * i + 3], q1);
    }
    float val = (q0 + q1) * __expf(e - mm);
    float s = val;
#pragma unroll
    for (int off = 32; off; off >>= 1) s += __shfl_xor(s, off);
    if ((tid & 63) == 0) red[4 + (tid >> 6)] = s;
    __syncthreads();
    s = (red[4] + red[5]) + (red[6] + red[7]);
    L += __logf(s) + mm;
    v_s[tid] = val * (1.0f / s);
  }
  if (partials) { if (tid == 0) partials[b] = L; }
  else { if (tid == 0) atomicAdd(out, L); }
}

// ---------------------------------------------------------------------------
// Finalize: deterministic tree-sum of per-sequence LLs + priors.
// ---------------------------------------------------------------------------
__global__ void fhmm_finalize(const float* __restrict__ partials,
                              const float* __restrict__ pw,
                              const float* __restrict__ px,
                              const float* __restrict__ py,
                              float* __restrict__ out)
{
  const int tid = threadIdx.x;
  float a = 0.f;
  if (partials) {
#pragma unroll
    for (int i = 0; i < 8; ++i) a += partials[tid + 256 * i];
  }
  {
    int i = tid >> 4, j = tid & 15;
    if (i != j) a += -0.9f * (logf(pw[tid]) + logf(px[tid]));
  }
  for (int k = 0; k < 64; ++k) {
    float p = py[tid * 64 + k];
    a += -0.9f * logf(p) - 0.1f * log1pf(-p);
  }
  __shared__ float red[256];
  red[tid] = a;
  __syncthreads();
  for (int s = 128; s > 0; s >>= 1) {
    if (tid < s) red[tid] += red[tid + s];
    __syncthreads();
  }
  if (tid == 0) {
    const float cst =
        2.f * (16.f * 0.2846828704729192f - 240.f * 2.2527126517342055f)
        - (2.2527126517342055f + 0.0663762397347443f) * 16384.f;
    out[0] = red[0] + cst;
  }
}

extern "C" void kernel_launch(void* const* d_in, const int* in_sizes, int n_in,
                              void* d_out, int out_size, void* d_ws, size_t ws_size,
                              hipStream_t stream) {
  const int*   seq = (const int*)d_in[0];
  const int*   len = (const int*)d_in[1];
  const float* pw  = (const float*)d_in[2];
  const float* px  = (const float*)d_in[3];
  const float* py  = (const float*)d_in[4];
  float*       out = (float*)d_out;

  const size_t NEED = 65536;  // 32K wfrag + 16K base + 8K partials + 8K perm
  if (ws_size >= NEED) {
    unsigned short* wf = (unsigned short*)d_ws;
    float* partials = (float*)((char*)d_ws + 49152);
    int*   perm     = (int*)((char*)d_ws + 57344);
    fhmm_init_sort<<<13, 256, 0, stream>>>(py, len, wf, partials, perm);
    fhmm_fwd2<<<512, 256, 0, stream>>>(seq, len, pw, px, (const void*)wf, perm, partials);
    fhmm_finalize<<<1, 256, 0, stream>>>(partials, pw, px, py, out);
  } else if (ws_size >= 2048 * sizeof(float)) {
    float* partials = (float*)d_ws;
    fhmm_fwd1<<<NB, 256, 0, stream>>>(seq, len, pw, px, py, partials, out);
    fhmm_finalize<<<1, 256, 0, stream>>>(partials, pw, px, py, out);
  } else {
    fhmm_finalize<<<1, 256, 0, stream>>>(nullptr, pw, px, py, out);
    fhmm_fwd1<<<NB, 256, 0, stream>>>(seq, len, pw, px, py, nullptr, out);
  }
}